// Round 1
// baseline (2428.024 us; speedup 1.0000x reference)
//
#include <hip/hip_runtime.h>
#include <hip/hip_bf16.h>

#define EMBD 768
#define HS 64

// ---------------- QKV projection ----------------
// 16 rows per block, 192 threads: wave0 -> Q cols, wave1 -> K cols, wave2 -> V cols.
// x rows staged in LDS (48KB); LDS reads are wave-uniform broadcasts; W reads coalesced.
__global__ __launch_bounds__(192) void qkv_kernel(
    const float* __restrict__ x,
    const float* __restrict__ Wq, const float* __restrict__ Wk, const float* __restrict__ Wv,
    float* __restrict__ Q, float* __restrict__ K, float* __restrict__ V)
{
    __shared__ float xs[16 * EMBD];
    const int rb = blockIdx.x;         // block of 16 rows
    const int t  = threadIdx.x;        // 0..191

    const float4* x4  = reinterpret_cast<const float4*>(x + (size_t)rb * 16 * EMBD);
    float4*       xs4 = reinterpret_cast<float4*>(xs);
#pragma unroll
    for (int i = 0; i < 16; ++i)       // 16*192 = 3072 float4 = 16*768 floats
        xs4[i * 192 + t] = x4[i * 192 + t];
    __syncthreads();

    const int which = t >> 6;          // 0=Q,1=K,2=V (uniform per wave)
    const int h     = t & 63;
    const float* W = (which == 0) ? Wq : (which == 1) ? Wk : Wv;

    float acc[16];
#pragma unroll
    for (int r = 0; r < 16; ++r) acc[r] = 0.f;

    for (int e = 0; e < EMBD; ++e) {
        float w = W[e * HS + h];       // coalesced across lane=h
#pragma unroll
        for (int r = 0; r < 16; ++r)
            acc[r] = fmaf(xs[r * EMBD + e], w, acc[r]);   // LDS broadcast
    }

    float* Out = (which == 0) ? Q : (which == 1) ? K : V;
#pragma unroll
    for (int r = 0; r < 16; ++r)
        Out[(size_t)(rb * 16 + r) * HS + h] = acc[r];
}

// ---------------- Causal flash attention (fp32) ----------------
// One thread per query row. BQ=256 rows per block, K/V tiles of BK=64 staged in LDS.
// Online softmax with rescale-only-on-new-max.
#define BQ 256
#define BK 64

__global__ __launch_bounds__(256) void attn_kernel(
    const float* __restrict__ Q, const float* __restrict__ K, const float* __restrict__ V,
    float* __restrict__ out, int S)
{
    __shared__ float Ks[BK * HS];
    __shared__ float Vs[BK * HS];

    const int nqt = S / BQ;
    const int b   = blockIdx.x / nqt;
    const int qt  = blockIdx.x % nqt;
    const int t   = threadIdx.x;
    const int q   = qt * BQ + t;

    const float4* Qr4 = reinterpret_cast<const float4*>(Q + ((size_t)b * S + q) * HS);
    float4 qv[16];
#pragma unroll
    for (int i = 0; i < 16; ++i) qv[i] = Qr4[i];

    float4 acc[16];
#pragma unroll
    for (int i = 0; i < 16; ++i) acc[i] = make_float4(0.f, 0.f, 0.f, 0.f);
    float m = -1e30f, l = 0.f;
    const float scale = 0.125f;        // 1/sqrt(64)

    const int ntiles = (qt * BQ + BQ) / BK;   // keys needed by the block's max q
    const float* Kb = K + (size_t)b * S * HS;
    const float* Vb = V + (size_t)b * S * HS;

    for (int kb = 0; kb < ntiles; ++kb) {
        __syncthreads();
        // stage K/V tile: 64 rows x 64 floats = 1024 float4 each, 4 per thread
        const float4* Ksrc = reinterpret_cast<const float4*>(Kb + (size_t)kb * BK * HS);
        const float4* Vsrc = reinterpret_cast<const float4*>(Vb + (size_t)kb * BK * HS);
        float4* Kd = reinterpret_cast<float4*>(Ks);
        float4* Vd = reinterpret_cast<float4*>(Vs);
#pragma unroll
        for (int i = 0; i < 4; ++i) {
            Kd[i * 256 + t] = Ksrc[i * 256 + t];
            Vd[i * 256 + t] = Vsrc[i * 256 + t];
        }
        __syncthreads();

        const int kmax  = q - kb * BK;             // causal: process kk <= kmax
        const int kkend = (kmax < BK - 1) ? kmax : (BK - 1);
        for (int kk = 0; kk <= kkend; ++kk) {      // lanes with kmax<0 skip entirely
            const float4* Krow = reinterpret_cast<const float4*>(Ks + kk * HS);
            float4 s4 = make_float4(0.f, 0.f, 0.f, 0.f);
#pragma unroll
            for (int i = 0; i < 16; ++i) {
                float4 kv = Krow[i];               // LDS broadcast (uniform addr)
                s4.x = fmaf(qv[i].x, kv.x, s4.x);
                s4.y = fmaf(qv[i].y, kv.y, s4.y);
                s4.z = fmaf(qv[i].z, kv.z, s4.z);
                s4.w = fmaf(qv[i].w, kv.w, s4.w);
            }
            float s = ((s4.x + s4.y) + (s4.z + s4.w)) * scale;

            if (s > m) {                           // rare rescale
                float corr = __expf(m - s);
                l *= corr;
#pragma unroll
                for (int i = 0; i < 16; ++i) {
                    acc[i].x *= corr; acc[i].y *= corr;
                    acc[i].z *= corr; acc[i].w *= corr;
                }
                m = s;
            }
            float p = __expf(s - m);
            l += p;
            const float4* Vrow = reinterpret_cast<const float4*>(Vs + kk * HS);
#pragma unroll
            for (int i = 0; i < 16; ++i) {
                float4 vv = Vrow[i];               // LDS broadcast
                acc[i].x = fmaf(p, vv.x, acc[i].x);
                acc[i].y = fmaf(p, vv.y, acc[i].y);
                acc[i].z = fmaf(p, vv.z, acc[i].z);
                acc[i].w = fmaf(p, vv.w, acc[i].w);
            }
        }
    }

    const float inv = 1.f / l;                     // k==q always processed -> l >= 1
    float4* out4 = reinterpret_cast<float4*>(out + ((size_t)b * S + q) * HS);
#pragma unroll
    for (int i = 0; i < 16; ++i)
        out4[i] = make_float4(acc[i].x * inv, acc[i].y * inv, acc[i].z * inv, acc[i].w * inv);
}

extern "C" void kernel_launch(void* const* d_in, const int* in_sizes, int n_in,
                              void* d_out, int out_size, void* d_ws, size_t ws_size,
                              hipStream_t stream) {
    const float* x  = (const float*)d_in[0];
    const float* Wq = (const float*)d_in[1];
    const float* Wk = (const float*)d_in[2];
    const float* Wv = (const float*)d_in[3];
    float* out = (float*)d_out;
    float* ws  = (float*)d_ws;

    const int S    = 4096;
    const int rows = in_sizes[0] / EMBD;   // B*S = 16384
    const int B    = rows / S;

    size_t per = (size_t)rows * HS;        // floats per Q/K/V buffer
    float* Qb = ws;
    float* Kb = ws + per;
    float* Vb = ws + 2 * per;

    hipLaunchKernelGGL(qkv_kernel, dim3(rows / 16), dim3(192), 0, stream,
                       x, Wq, Wk, Wv, Qb, Kb, Vb);
    hipLaunchKernelGGL(attn_kernel, dim3(B * (S / BQ)), dim3(256), 0, stream,
                       Qb, Kb, Vb, out, S);
}

// Round 2
// 216.261 us; speedup vs baseline: 11.2273x; 11.2273x over previous
//
#include <hip/hip_runtime.h>

#define EMBD 768
#define HS 64
#define S_LEN 4096
#define BK 32

typedef __attribute__((ext_vector_type(8))) short short8;
typedef __attribute__((ext_vector_type(4))) float f32x4;
typedef unsigned short ushort_t;

static __device__ __forceinline__ ushort_t f2bf(float f) {
    union { float f; unsigned u; } x; x.f = f;
    unsigned r = x.u + 0x7fffu + ((x.u >> 16) & 1u);   // RNE
    return (ushort_t)(r >> 16);
}

// ---------------- QKV projection (fp32 in, bf16 out; V transposed) ----------------
__global__ __launch_bounds__(192) void qkv_kernel(
    const float* __restrict__ x,
    const float* __restrict__ Wq, const float* __restrict__ Wk, const float* __restrict__ Wv,
    ushort_t* __restrict__ Qg, ushort_t* __restrict__ Kg, ushort_t* __restrict__ Vtg)
{
    __shared__ float xs[16 * EMBD];
    const int rb = blockIdx.x;
    const int t  = threadIdx.x;

    const float4* x4  = (const float4*)(x + (size_t)rb * 16 * EMBD);
    float4* xs4 = (float4*)xs;
#pragma unroll
    for (int i = 0; i < 16; ++i) xs4[i * 192 + t] = x4[i * 192 + t];
    __syncthreads();

    const int which = t >> 6;          // wave 0->Q, 1->K, 2->V
    const int h     = t & 63;
    const float* W  = (which == 0) ? Wq : (which == 1) ? Wk : Wv;
    const float* Wp = W + h;

    float acc[16];
#pragma unroll
    for (int r = 0; r < 16; ++r) acc[r] = 0.f;

    for (int e = 0; e < EMBD; e += 4) {
        float w0 = Wp[(e+0)*HS], w1 = Wp[(e+1)*HS], w2 = Wp[(e+2)*HS], w3 = Wp[(e+3)*HS];
#pragma unroll
        for (int r = 0; r < 16; ++r) {
            float4 xv = *(const float4*)&xs[r*EMBD + e];   // wave-uniform b128 broadcast
            acc[r] = fmaf(xv.w, w3, fmaf(xv.z, w2, fmaf(xv.y, w1, fmaf(xv.x, w0, acc[r]))));
        }
    }

    const int row0 = rb * 16;
    if (which < 2) {
        ushort_t* Out = (which == 0) ? Qg : Kg;
#pragma unroll
        for (int r = 0; r < 16; ++r) Out[(size_t)(row0 + r) * HS + h] = f2bf(acc[r]);
    } else {
        const int b = row0 / S_LEN, s0 = row0 % S_LEN;
#pragma unroll
        for (int r = 0; r < 16; ++r)
            Vtg[((size_t)b * HS + h) * S_LEN + s0 + r] = f2bf(acc[r]);
    }
}

// ---------------- MFMA flash attention ----------------
// Block = one 16-row q-tile; 4 waves split the key tiles (kb = w, w+4, ...),
// wave-private swizzled LDS staging, in-block combine of partial (m,l,acc).
__global__ __launch_bounds__(256) void attn_kernel(
    const ushort_t* __restrict__ Qg, const ushort_t* __restrict__ Kg,
    const ushort_t* __restrict__ Vtg, float* __restrict__ out, int B)
{
    __shared__ char smem[4 * 9216];    // per wave: K 4KB | Vt 4KB | P 1KB
    const int t    = threadIdx.x;
    const int w    = t >> 6;
    const int lane = t & 63;
    const int l15  = lane & 15;
    const int l4   = lane >> 4;

    const int b  = blockIdx.x % B;
    const int qt = 255 - (blockIdx.x / B);   // biggest tiles dispatched first
    const int q0 = qt * 16;
    const int ntiles = (qt + 2) >> 1;        // ceil((q0+16)/32)

    char* my  = smem + w * 9216;
    char* myK = my;                          // [32 keys][64 d] bf16, row^((row&7)<<4)
    char* myV = my + 4096;                   // [64 d][32 keys] bf16, row^(((row>>1)&3)<<4)
    char* myP = my + 8192;                   // [16 q][32 keys] bf16, same swizzle as V

    // Q fragments (all 4 waves load the same 16 q rows)
    const ushort_t* Qrow = Qg + ((size_t)(b * S_LEN) + q0 + l15) * HS;
    short8 qf0 = *(const short8*)(Qrow + l4 * 8);
    short8 qf1 = *(const short8*)(Qrow + 32 + l4 * 8);

    f32x4 acc[4];
#pragma unroll
    for (int i = 0; i < 4; ++i) acc[i] = (f32x4){0.f, 0.f, 0.f, 0.f};
    float m[4]    = {-1e30f, -1e30f, -1e30f, -1e30f};
    float lsum[4] = {0.f, 0.f, 0.f, 0.f};

    const ushort_t* Kbase = Kg + (size_t)b * S_LEN * HS;
    const ushort_t* Vbase = Vtg + (size_t)b * HS * S_LEN;

    for (int kb = w; kb < ntiles; kb += 4) {
        // ---- wave-private staging (no barriers; same-wave lgkmcnt ordering)
        const ushort_t* Ksrc = Kbase + (size_t)kb * BK * HS;
#pragma unroll
        for (int i = 0; i < 4; ++i) {
            int c = i * 64 + lane;
            { int row = c >> 3, col = c & 7;
              short8 v = *(const short8*)(Ksrc + row * HS + col * 8);
              *(short8*)(myK + row * 128 + ((col * 16) ^ ((row & 7) << 4))) = v; }
            { int row = c >> 2, col = c & 3;
              short8 v = *(const short8*)(Vbase + (size_t)row * S_LEN + kb * BK + col * 8);
              *(short8*)(myV + row * 64 + ((col * 16) ^ (((row >> 1) & 3) << 4))) = v; }
        }

        // ---- QK^T: S[16q][32keys], lane holds S[l4*4+r][st*16+l15]
        f32x4 s[2];
#pragma unroll
        for (int st = 0; st < 2; ++st) {
            int row = st * 16 + l15;
            int rb_ = row * 128, sw = (row & 7) << 4;
            short8 k0 = *(const short8*)(myK + rb_ + ((l4 * 16) ^ sw));
            short8 k1 = *(const short8*)(myK + rb_ + ((64 + l4 * 16) ^ sw));
            f32x4 z = (f32x4){0.f, 0.f, 0.f, 0.f};
            z = __builtin_amdgcn_mfma_f32_16x16x32_bf16(qf0, k0, z, 0, 0, 0);
            z = __builtin_amdgcn_mfma_f32_16x16x32_bf16(qf1, k1, z, 0, 0, 0);
            s[st] = z;
        }
        const bool maskTile = (kb == ntiles - 1);
#pragma unroll
        for (int st = 0; st < 2; ++st)
#pragma unroll
            for (int r = 0; r < 4; ++r) {
                float sv = s[st][r] * 0.125f;
                if (maskTile) {
                    int key = kb * BK + st * 16 + l15;
                    int q   = q0 + l4 * 4 + r;
                    if (key > q) sv = -1e30f;
                }
                s[st][r] = sv;
            }

        // ---- online softmax (row-max over 16 lanes + 2 in-lane)
        float p0[4], p1[4];
#pragma unroll
        for (int r = 0; r < 4; ++r) {
            float c = fmaxf(s[0][r], s[1][r]);
            c = fmaxf(c, __shfl_xor(c, 1));
            c = fmaxf(c, __shfl_xor(c, 2));
            c = fmaxf(c, __shfl_xor(c, 4));
            c = fmaxf(c, __shfl_xor(c, 8));
            float mn   = fmaxf(m[r], c);
            float corr = __expf(m[r] - mn);
            m[r] = mn;
            p0[r] = __expf(s[0][r] - mn);
            p1[r] = __expf(s[1][r] - mn);
            lsum[r] = lsum[r] * corr + p0[r] + p1[r];
#pragma unroll
            for (int d = 0; d < 4; ++d) acc[d][r] *= corr;
        }

        // ---- P -> LDS (bf16), resolves C/D -> A-fragment layout mismatch
#pragma unroll
        for (int r = 0; r < 4; ++r) {
            int q = l4 * 4 + r;
            int base = q * 64, sw = ((q >> 1) & 3) << 4;
            *(ushort_t*)(myP + base + ((l15 * 2) ^ sw))        = f2bf(p0[r]);
            *(ushort_t*)(myP + base + ((32 + l15 * 2) ^ sw))   = f2bf(p1[r]);
        }

        // ---- PV: O[16q][64d] += P[16x32] * V[32x64]
        {
            short8 pa = *(const short8*)(myP + l15 * 64 + ((l4 * 16) ^ (((l15 >> 1) & 3) << 4)));
#pragma unroll
            for (int ds = 0; ds < 4; ++ds) {
                int row = ds * 16 + l15;
                short8 vb = *(const short8*)(myV + row * 64 + ((l4 * 16) ^ (((row >> 1) & 3) << 4)));
                acc[ds] = __builtin_amdgcn_mfma_f32_16x16x32_bf16(pa, vb, acc[ds], 0, 0, 0);
            }
        }
    }

    // ---- reduce l across the 16 lanes of each q-group
#pragma unroll
    for (int r = 0; r < 4; ++r) {
        lsum[r] += __shfl_xor(lsum[r], 1);
        lsum[r] += __shfl_xor(lsum[r], 2);
        lsum[r] += __shfl_xor(lsum[r], 4);
        lsum[r] += __shfl_xor(lsum[r], 8);
    }

    // ---- in-block combine of 4 key-split partials
    __syncthreads();
    float* accb = (float*)smem;                  // [4][16][64]
    float* mb   = (float*)(smem + 16384);        // [4][16]
    float* lb   = (float*)(smem + 16384 + 256);  // [4][16]
#pragma unroll
    for (int ds = 0; ds < 4; ++ds)
#pragma unroll
        for (int r = 0; r < 4; ++r)
            accb[(w * 16 + l4 * 4 + r) * 64 + ds * 16 + l15] = acc[ds][r];
    if (l15 == 0)
#pragma unroll
        for (int r = 0; r < 4; ++r) {
            mb[w * 16 + l4 * 4 + r] = m[r];
            lb[w * 16 + l4 * 4 + r] = lsum[r];
        }
    __syncthreads();

    const int d = t & 63;
#pragma unroll
    for (int pass = 0; pass < 4; ++pass) {
        int row = (t >> 6) + pass * 4;
        float m0 = mb[row], m1 = mb[16 + row], m2 = mb[32 + row], m3 = mb[48 + row];
        float ms = fmaxf(fmaxf(m0, m1), fmaxf(m2, m3));
        float e0 = __expf(m0 - ms), e1 = __expf(m1 - ms), e2 = __expf(m2 - ms), e3 = __expf(m3 - ms);
        float o  = accb[(0 * 16 + row) * 64 + d] * e0 + accb[(1 * 16 + row) * 64 + d] * e1
                 + accb[(2 * 16 + row) * 64 + d] * e2 + accb[(3 * 16 + row) * 64 + d] * e3;
        float ll = lb[row] * e0 + lb[16 + row] * e1 + lb[32 + row] * e2 + lb[48 + row] * e3;
        out[((size_t)(b * S_LEN) + q0 + row) * HS + d] = o / ll;
    }
}

extern "C" void kernel_launch(void* const* d_in, const int* in_sizes, int n_in,
                              void* d_out, int out_size, void* d_ws, size_t ws_size,
                              hipStream_t stream) {
    const float* x  = (const float*)d_in[0];
    const float* Wq = (const float*)d_in[1];
    const float* Wk = (const float*)d_in[2];
    const float* Wv = (const float*)d_in[3];
    float* out = (float*)d_out;

    const int rows = in_sizes[0] / EMBD;   // B*S
    const int B    = rows / S_LEN;

    ushort_t* Qb = (ushort_t*)d_ws;
    ushort_t* Kb = Qb + (size_t)rows * HS;
    ushort_t* Vt = Kb + (size_t)rows * HS;

    hipLaunchKernelGGL(qkv_kernel, dim3(rows / 16), dim3(192), 0, stream,
                       x, Wq, Wk, Wv, Qb, Kb, Vt);
    hipLaunchKernelGGL(attn_kernel, dim3(B * 256), dim3(256), 0, stream,
                       Qb, Kb, Vt, out, B);
}

// Round 3
// 90.079 us; speedup vs baseline: 26.9542x; 2.4008x over previous
//
#include <hip/hip_runtime.h>

#define EMBD 768
#define HS 64
#define S_LEN 4096
#define BK 32

typedef __attribute__((ext_vector_type(8))) short short8;
typedef __attribute__((ext_vector_type(4))) short short4_t;
typedef __attribute__((ext_vector_type(4))) float f32x4;
typedef unsigned short ushort_t;

static __device__ __forceinline__ ushort_t f2bf(float f) {
    union { float f; unsigned u; } x; x.f = f;
    unsigned r = x.u + 0x7fffu + ((x.u >> 16) & 1u);   // RNE
    return (ushort_t)(r >> 16);
}

// ---------------- W prep: Wt[192][768] bf16, Wt[c][k] = W_sel[k][c%64] ----------------
__global__ __launch_bounds__(256) void wprep_kernel(
    const float* __restrict__ Wq, const float* __restrict__ Wk, const float* __restrict__ Wv,
    ushort_t* __restrict__ Wt)
{
    const int c = blockIdx.x;                  // 0..191
    const float* W = (c < 64) ? Wq : (c < 128) ? Wk : Wv;
    const int col = c & 63;
    for (int k = threadIdx.x; k < EMBD; k += 256)
        Wt[(size_t)c * EMBD + k] = f2bf(W[(size_t)k * HS + col]);
}

// ---------------- QKV projection via MFMA ----------------
// Block: 32 rows x 192 cols. 8 waves = 2 row-groups x 4 col-groups; each wave owns
// one Q, one K, one V 16-col tile. Double-buffered swizzled LDS x-tile (bf16).
__global__ __launch_bounds__(512) void qkv_kernel(
    const float* __restrict__ x, const ushort_t* __restrict__ Wt,
    ushort_t* __restrict__ Qg, ushort_t* __restrict__ Kg, ushort_t* __restrict__ Vtg)
{
    __shared__ char xsb[2][32 * 128];          // [32 rows][64 k] bf16, swizzled
    __shared__ float Vs[32][65];               // V transpose buffer (padded)
    const int t    = threadIdx.x;
    const int w    = t >> 6;
    const int lane = t & 63;
    const int l15  = lane & 15;
    const int l4   = lane >> 4;
    const int mg   = w >> 2;                   // row-group 0/1
    const int cg   = w & 3;                    // col-group 0..3
    const int row0 = blockIdx.x * 32;

    // staging: thread t loads x[row0 + t/16][(t%16)*4 .. +3] per K-tile
    const int srow  = t >> 4;
    const int wbyte = srow * 128 + (((t & 15) * 8) ^ ((srow & 7) << 4));
    const float* xsrc = x + (size_t)(row0 + srow) * EMBD + (t & 15) * 4;

    // A-fragment read address (per wave: rows mg*16..+15)
    const int arow  = mg * 16 + l15;
    const int abase = arow * 128;
    const int asw   = (arow & 7) << 4;

    // B-fragment base pointers (col-tiles: cg -> Q, 4+cg -> K, 8+cg -> V)
    const ushort_t* wp0 = Wt + (size_t)(cg * 16 + l15) * EMBD + l4 * 8;
    const ushort_t* wp1 = wp0 + (size_t)64 * EMBD;
    const ushort_t* wp2 = wp0 + (size_t)128 * EMBD;

    f32x4 acc0 = (f32x4){0.f,0.f,0.f,0.f}, acc1 = acc0, acc2 = acc0;

    // prologue: stage K-tile 0
    {
        float4 xv = *(const float4*)xsrc;
        short4_t p = {(short)f2bf(xv.x), (short)f2bf(xv.y), (short)f2bf(xv.z), (short)f2bf(xv.w)};
        *(short4_t*)(xsb[0] + wbyte) = p;
    }

    for (int kt = 0; kt < 12; ++kt) {
        const int cur = kt & 1;
        __syncthreads();                        // buffer `cur` ready
        float4 xnext;
        if (kt < 11) xnext = *(const float4*)(xsrc + (kt + 1) * 64);   // issue early
#pragma unroll
        for (int ks = 0; ks < 2; ++ks) {
            short8 af = *(const short8*)(xsb[cur] + abase + ((ks * 64 + l4 * 16) ^ asw));
            const int ko = kt * 64 + ks * 32;
            short8 b0 = *(const short8*)(wp0 + ko);
            short8 b1 = *(const short8*)(wp1 + ko);
            short8 b2 = *(const short8*)(wp2 + ko);
            acc0 = __builtin_amdgcn_mfma_f32_16x16x32_bf16(af, b0, acc0, 0, 0, 0);
            acc1 = __builtin_amdgcn_mfma_f32_16x16x32_bf16(af, b1, acc1, 0, 0, 0);
            acc2 = __builtin_amdgcn_mfma_f32_16x16x32_bf16(af, b2, acc2, 0, 0, 0);
        }
        if (kt < 11) {                          // write late (hidden under MFMAs)
            short4_t p = {(short)f2bf(xnext.x), (short)f2bf(xnext.y), (short)f2bf(xnext.z), (short)f2bf(xnext.w)};
            *(short4_t*)(xsb[cur ^ 1] + wbyte) = p;
        }
    }

    // epilogue: Q/K direct, V via LDS transpose
    const size_t grow0 = (size_t)row0 + mg * 16 + l4 * 4;
    const int col = cg * 16 + l15;
#pragma unroll
    for (int r = 0; r < 4; ++r) {
        Qg[(grow0 + r) * HS + col] = f2bf(acc0[r]);
        Kg[(grow0 + r) * HS + col] = f2bf(acc1[r]);
        Vs[mg * 16 + l4 * 4 + r][col] = acc2[r];
    }
    __syncthreads();
    const int vcol = t >> 3, vr0 = (t & 7) * 4;
    const int bb = row0 >> 12, s0 = row0 & 4095;
    short4_t vp = {(short)f2bf(Vs[vr0][vcol]),     (short)f2bf(Vs[vr0 + 1][vcol]),
                   (short)f2bf(Vs[vr0 + 2][vcol]), (short)f2bf(Vs[vr0 + 3][vcol])};
    *(short4_t*)(Vtg + ((size_t)bb * HS + vcol) * S_LEN + s0 + vr0) = vp;
}

// ---------------- MFMA flash attention (unchanged from R2) ----------------
__global__ __launch_bounds__(256) void attn_kernel(
    const ushort_t* __restrict__ Qg, const ushort_t* __restrict__ Kg,
    const ushort_t* __restrict__ Vtg, float* __restrict__ out, int B)
{
    __shared__ char smem[4 * 9216];
    const int t    = threadIdx.x;
    const int w    = t >> 6;
    const int lane = t & 63;
    const int l15  = lane & 15;
    const int l4   = lane >> 4;

    const int b  = blockIdx.x % B;
    const int qt = 255 - (blockIdx.x / B);
    const int q0 = qt * 16;
    const int ntiles = (qt + 2) >> 1;

    char* my  = smem + w * 9216;
    char* myK = my;
    char* myV = my + 4096;
    char* myP = my + 8192;

    const ushort_t* Qrow = Qg + ((size_t)(b * S_LEN) + q0 + l15) * HS;
    short8 qf0 = *(const short8*)(Qrow + l4 * 8);
    short8 qf1 = *(const short8*)(Qrow + 32 + l4 * 8);

    f32x4 acc[4];
#pragma unroll
    for (int i = 0; i < 4; ++i) acc[i] = (f32x4){0.f, 0.f, 0.f, 0.f};
    float m[4]    = {-1e30f, -1e30f, -1e30f, -1e30f};
    float lsum[4] = {0.f, 0.f, 0.f, 0.f};

    const ushort_t* Kbase = Kg + (size_t)b * S_LEN * HS;
    const ushort_t* Vbase = Vtg + (size_t)b * HS * S_LEN;

    for (int kb = w; kb < ntiles; kb += 4) {
        const ushort_t* Ksrc = Kbase + (size_t)kb * BK * HS;
#pragma unroll
        for (int i = 0; i < 4; ++i) {
            int c = i * 64 + lane;
            { int row = c >> 3, colc = c & 7;
              short8 v = *(const short8*)(Ksrc + row * HS + colc * 8);
              *(short8*)(myK + row * 128 + ((colc * 16) ^ ((row & 7) << 4))) = v; }
            { int row = c >> 2, colc = c & 3;
              short8 v = *(const short8*)(Vbase + (size_t)row * S_LEN + kb * BK + colc * 8);
              *(short8*)(myV + row * 64 + ((colc * 16) ^ (((row >> 1) & 3) << 4))) = v; }
        }

        f32x4 s[2];
#pragma unroll
        for (int st = 0; st < 2; ++st) {
            int row = st * 16 + l15;
            int rb_ = row * 128, sw = (row & 7) << 4;
            short8 k0 = *(const short8*)(myK + rb_ + ((l4 * 16) ^ sw));
            short8 k1 = *(const short8*)(myK + rb_ + ((64 + l4 * 16) ^ sw));
            f32x4 z = (f32x4){0.f, 0.f, 0.f, 0.f};
            z = __builtin_amdgcn_mfma_f32_16x16x32_bf16(qf0, k0, z, 0, 0, 0);
            z = __builtin_amdgcn_mfma_f32_16x16x32_bf16(qf1, k1, z, 0, 0, 0);
            s[st] = z;
        }
        const bool maskTile = (kb == ntiles - 1);
#pragma unroll
        for (int st = 0; st < 2; ++st)
#pragma unroll
            for (int r = 0; r < 4; ++r) {
                float sv = s[st][r] * 0.125f;
                if (maskTile) {
                    int key = kb * BK + st * 16 + l15;
                    int q   = q0 + l4 * 4 + r;
                    if (key > q) sv = -1e30f;
                }
                s[st][r] = sv;
            }

        float p0[4], p1[4];
#pragma unroll
        for (int r = 0; r < 4; ++r) {
            float c = fmaxf(s[0][r], s[1][r]);
            c = fmaxf(c, __shfl_xor(c, 1));
            c = fmaxf(c, __shfl_xor(c, 2));
            c = fmaxf(c, __shfl_xor(c, 4));
            c = fmaxf(c, __shfl_xor(c, 8));
            float mn   = fmaxf(m[r], c);
            float corr = __expf(m[r] - mn);
            m[r] = mn;
            p0[r] = __expf(s[0][r] - mn);
            p1[r] = __expf(s[1][r] - mn);
            lsum[r] = lsum[r] * corr + p0[r] + p1[r];
#pragma unroll
            for (int d = 0; d < 4; ++d) acc[d][r] *= corr;
        }

#pragma unroll
        for (int r = 0; r < 4; ++r) {
            int q = l4 * 4 + r;
            int base = q * 64, sw = ((q >> 1) & 3) << 4;
            *(ushort_t*)(myP + base + ((l15 * 2) ^ sw))      = f2bf(p0[r]);
            *(ushort_t*)(myP + base + ((32 + l15 * 2) ^ sw)) = f2bf(p1[r]);
        }

        {
            short8 pa = *(const short8*)(myP + l15 * 64 + ((l4 * 16) ^ (((l15 >> 1) & 3) << 4)));
#pragma unroll
            for (int ds = 0; ds < 4; ++ds) {
                int row = ds * 16 + l15;
                short8 vb = *(const short8*)(myV + row * 64 + ((l4 * 16) ^ (((row >> 1) & 3) << 4)));
                acc[ds] = __builtin_amdgcn_mfma_f32_16x16x32_bf16(pa, vb, acc[ds], 0, 0, 0);
            }
        }
    }

#pragma unroll
    for (int r = 0; r < 4; ++r) {
        lsum[r] += __shfl_xor(lsum[r], 1);
        lsum[r] += __shfl_xor(lsum[r], 2);
        lsum[r] += __shfl_xor(lsum[r], 4);
        lsum[r] += __shfl_xor(lsum[r], 8);
    }

    __syncthreads();
    float* accb = (float*)smem;
    float* mb   = (float*)(smem + 16384);
    float* lb   = (float*)(smem + 16384 + 256);
#pragma unroll
    for (int ds = 0; ds < 4; ++ds)
#pragma unroll
        for (int r = 0; r < 4; ++r)
            accb[(w * 16 + l4 * 4 + r) * 64 + ds * 16 + l15] = acc[ds][r];
    if (l15 == 0)
#pragma unroll
        for (int r = 0; r < 4; ++r) {
            mb[w * 16 + l4 * 4 + r] = m[r];
            lb[w * 16 + l4 * 4 + r] = lsum[r];
        }
    __syncthreads();

    const int d = t & 63;
#pragma unroll
    for (int pass = 0; pass < 4; ++pass) {
        int row = (t >> 6) + pass * 4;
        float m0 = mb[row], m1 = mb[16 + row], m2 = mb[32 + row], m3 = mb[48 + row];
        float ms = fmaxf(fmaxf(m0, m1), fmaxf(m2, m3));
        float e0 = __expf(m0 - ms), e1 = __expf(m1 - ms), e2 = __expf(m2 - ms), e3 = __expf(m3 - ms);
        float o  = accb[(0 * 16 + row) * 64 + d] * e0 + accb[(1 * 16 + row) * 64 + d] * e1
                 + accb[(2 * 16 + row) * 64 + d] * e2 + accb[(3 * 16 + row) * 64 + d] * e3;
        float ll = lb[row] * e0 + lb[16 + row] * e1 + lb[32 + row] * e2 + lb[48 + row] * e3;
        out[((size_t)(b * S_LEN) + q0 + row) * HS + d] = o / ll;
    }
}

extern "C" void kernel_launch(void* const* d_in, const int* in_sizes, int n_in,
                              void* d_out, int out_size, void* d_ws, size_t ws_size,
                              hipStream_t stream) {
    const float* x  = (const float*)d_in[0];
    const float* Wq = (const float*)d_in[1];
    const float* Wk = (const float*)d_in[2];
    const float* Wv = (const float*)d_in[3];
    float* out = (float*)d_out;

    const int rows = in_sizes[0] / EMBD;   // B*S
    const int B    = rows / S_LEN;

    ushort_t* Qb = (ushort_t*)d_ws;
    ushort_t* Kb = Qb + (size_t)rows * HS;
    ushort_t* Vt = Kb + (size_t)rows * HS;
    ushort_t* Wt = Vt + (size_t)rows * HS;

    hipLaunchKernelGGL(wprep_kernel, dim3(192), dim3(256), 0, stream, Wq, Wk, Wv, Wt);
    hipLaunchKernelGGL(qkv_kernel, dim3(rows / 32), dim3(512), 0, stream,
                       x, Wt, Qb, Kb, Vt);
    hipLaunchKernelGGL(attn_kernel, dim3(B * 256), dim3(256), 0, stream,
                       Qb, Kb, Vt, out, B);
}